// Round 4
// 1616.251 us; speedup vs baseline: 2.3459x; 2.3459x over previous
//
#include <hip/hip_runtime.h>

static constexpr int Bc  = 8;
static constexpr int Sc  = 2048;
static constexpr int Hc  = 4;
static constexpr int DKc = 64;
static constexpr int DMc = 256;
static constexpr int TQ  = 4;   // q-rows per attn block (L2-reuse tile); LDS < 64 KB
static constexpr int TR  = 8;   // (b,s) rows per proj/out block

__device__ __forceinline__ float waveReduceMax(float v) {
#pragma unroll
  for (int o = 32; o > 0; o >>= 1) v = fmaxf(v, __shfl_down(v, o, 64));
  return v;
}
__device__ __forceinline__ float waveReduceSum(float v) {
#pragma unroll
  for (int o = 32; o > 0; o >>= 1) v += __shfl_down(v, o, 64);
  return v;
}

// One block per 8 consecutive (b,s) rows. Weights are read once per block and
// applied to 8 input rows staged in LDS (8x less L2 weight traffic).
__global__ __launch_bounds__(256) void proj_kernel(
    const float* __restrict__ q, const float* __restrict__ k, const float* __restrict__ v,
    const float* __restrict__ Wq, const float* __restrict__ bq,
    const float* __restrict__ Wk, const float* __restrict__ bk,
    const float* __restrict__ Wv, const float* __restrict__ bv,
    float* __restrict__ qs, float* __restrict__ ksT, float* __restrict__ vs) {
  const int bs0 = blockIdx.x * TR;     // 8 rows, same b (S % TR == 0)
  const int b   = bs0 >> 11;
  const int s0  = bs0 & (Sc - 1);
  const int tid = threadIdx.x;
  __shared__ float qrow[TR][DMc], krow[TR][DMc], vrow[TR][DMc];  // 24 KB
  {
    const float4* qg = (const float4*)(q + (size_t)bs0 * DMc);
    const float4* kg = (const float4*)(k + (size_t)bs0 * DMc);
    const float4* vg = (const float4*)(v + (size_t)bs0 * DMc);
    float4* qls = (float4*)&qrow[0][0];
    float4* kls = (float4*)&krow[0][0];
    float4* vls = (float4*)&vrow[0][0];
#pragma unroll
    for (int i = 0; i < 2; ++i) {
      qls[tid + i * 256] = qg[tid + i * 256];
      kls[tid + i * 256] = kg[tid + i * 256];
      vls[tid + i * 256] = vg[tid + i * 256];
    }
  }
  __syncthreads();
  const int h = tid >> 6, e = tid & 63;
  const float4* wq4 = (const float4*)(Wq + (size_t)(h * DKc + e) * DMc);
  const float4* wk4 = (const float4*)(Wk + (size_t)(h * DKc + e) * DMc);
  const float4* wv4 = (const float4*)(Wv + (size_t)e * DMc);
  const int rv = h * 2;                // each wave owns 2 vs rows -> balanced
  float accq[TR], acck[TR];
  float accv0 = 0.f, accv1 = 0.f;
#pragma unroll
  for (int r = 0; r < TR; ++r) { accq[r] = 0.f; acck[r] = 0.f; }
#pragma unroll 4
  for (int i = 0; i < DMc / 4; ++i) {
    const float4 wa = wq4[i], wc = wk4[i], wv = wv4[i];
#pragma unroll
    for (int r = 0; r < TR; ++r) {
      const float4 a = ((const float4*)qrow[r])[i];
      accq[r] += a.x * wa.x + a.y * wa.y + a.z * wa.z + a.w * wa.w;
      const float4 c = ((const float4*)krow[r])[i];
      acck[r] += c.x * wc.x + c.y * wc.y + c.z * wc.z + c.w * wc.w;
    }
    const float4 a0 = ((const float4*)vrow[rv])[i];
    const float4 a1 = ((const float4*)vrow[rv + 1])[i];
    accv0 += a0.x * wv.x + a0.y * wv.y + a0.z * wv.z + a0.w * wv.w;
    accv1 += a1.x * wv.x + a1.y * wv.y + a1.z * wv.z + a1.w * wv.w;
  }
  const float bqv = bq[h * DKc + e], bkv = bk[h * DKc + e];
#pragma unroll
  for (int r = 0; r < TR; ++r) {
    qs[((size_t)(b * Hc + h) * Sc + s0 + r) * DKc + e]  = accq[r] + bqv;
    ksT[((size_t)(b * Hc + h) * DKc + e) * Sc + s0 + r] = acck[r] + bkv;
  }
  const float bvv = bv[e];
  vs[(size_t)(bs0 + rv) * DKc + e]     = accv0 + bvv;
  vs[(size_t)(bs0 + rv + 1) * DKc + e] = accv1 + bvv;
}

// One block per (b,h, 4 q-rows). Each ksT float4 / vs element is loaded once
// from L2 and FMA'd into 4 row-accumulators -> 4x less L2 traffic.
__global__ __launch_bounds__(256) void attn_kernel(
    const float* __restrict__ qs, const float* __restrict__ ksT,
    const float* __restrict__ vs, float* __restrict__ attn,
    float* __restrict__ heads) {
  const int q0  = blockIdx.x * TQ;
  const int h   = blockIdx.y;
  const int b   = blockIdx.z;
  const int tid = threadIdx.x;
  __shared__ float sc[TQ][Sc];            // 32 KB
  __shared__ float qv[TQ][DKc];           // 1 KB
  __shared__ float wred[TQ][4], sred[TQ][4];
  __shared__ float hred[4][TQ][DKc];      // 4 KB  (total ~37.3 KB)

  {  // 4 q rows are contiguous: 256 floats, one per thread
    const float* qsrc = qs + ((size_t)(b * Hc + h) * Sc + q0) * DKc;
    (&qv[0][0])[tid] = qsrc[tid];
  }
  __syncthreads();

  const float4* ksT4 = (const float4*)(ksT + (size_t)(b * Hc + h) * DKc * Sc);
  float lmax[TQ];
#pragma unroll
  for (int r = 0; r < TQ; ++r) lmax[r] = -1e30f;

#pragma unroll
  for (int j = 0; j < 2; ++j) {
    const int k4 = tid + j * 256;       // float4 column (512 per row)
    float4 acc[TQ];
#pragma unroll
    for (int r = 0; r < TQ; ++r) acc[r] = make_float4(0.f, 0.f, 0.f, 0.f);
#pragma unroll 4
    for (int e4 = 0; e4 < DKc / 4; ++e4) {
      const float4 kv0 = ksT4[(size_t)(4 * e4 + 0) * (Sc / 4) + k4];
      const float4 kv1 = ksT4[(size_t)(4 * e4 + 1) * (Sc / 4) + k4];
      const float4 kv2 = ksT4[(size_t)(4 * e4 + 2) * (Sc / 4) + k4];
      const float4 kv3 = ksT4[(size_t)(4 * e4 + 3) * (Sc / 4) + k4];
#pragma unroll
      for (int r = 0; r < TQ; ++r) {
        const float4 qe = ((const float4*)qv[r])[e4];   // LDS broadcast
        acc[r].x += qe.x * kv0.x + qe.y * kv1.x + qe.z * kv2.x + qe.w * kv3.x;
        acc[r].y += qe.x * kv0.y + qe.y * kv1.y + qe.z * kv2.y + qe.w * kv3.y;
        acc[r].z += qe.x * kv0.z + qe.y * kv1.z + qe.z * kv2.z + qe.w * kv3.z;
        acc[r].w += qe.x * kv0.w + qe.y * kv1.w + qe.z * kv2.w + qe.w * kv3.w;
      }
    }
#pragma unroll
    for (int r = 0; r < TQ; ++r) {
      float4 a = acc[r];
      a.x *= 0.125f; a.y *= 0.125f; a.z *= 0.125f; a.w *= 0.125f;
      ((float4*)sc[r])[k4] = a;
      lmax[r] = fmaxf(lmax[r], fmaxf(fmaxf(a.x, a.y), fmaxf(a.z, a.w)));
    }
  }

#pragma unroll
  for (int r = 0; r < TQ; ++r) {
    const float wm = waveReduceMax(lmax[r]);
    if ((tid & 63) == 0) wred[r][tid >> 6] = wm;
  }
  __syncthreads();
  float gmax[TQ];
#pragma unroll
  for (int r = 0; r < TQ; ++r)
    gmax[r] = fmaxf(fmaxf(wred[r][0], wred[r][1]), fmaxf(wred[r][2], wred[r][3]));

  float lsum[TQ];
#pragma unroll
  for (int r = 0; r < TQ; ++r) lsum[r] = 0.f;
#pragma unroll
  for (int j = 0; j < 2; ++j) {
    const int k4 = tid + j * 256;
#pragma unroll
    for (int r = 0; r < TQ; ++r) {
      float4 a = ((float4*)sc[r])[k4];
      a.x = __expf(a.x - gmax[r]); a.y = __expf(a.y - gmax[r]);
      a.z = __expf(a.z - gmax[r]); a.w = __expf(a.w - gmax[r]);
      ((float4*)sc[r])[k4] = a;
      lsum[r] += a.x + a.y + a.z + a.w;
    }
  }
#pragma unroll
  for (int r = 0; r < TQ; ++r) {
    const float ws = waveReduceSum(lsum[r]);
    if ((tid & 63) == 0) sred[r][tid >> 6] = ws;
  }
  __syncthreads();
  float inv[TQ];
#pragma unroll
  for (int r = 0; r < TQ; ++r)
    inv[r] = 1.f / (sred[r][0] + sred[r][1] + sred[r][2] + sred[r][3]);

#pragma unroll
  for (int r = 0; r < TQ; ++r) {
    float4* arow = (float4*)(attn + ((size_t)(b * Sc + q0 + r) * Hc + h) * Sc);
#pragma unroll
    for (int j = 0; j < 2; ++j) {
      const int k4 = tid + j * 256;
      float4 a = ((float4*)sc[r])[k4];
      a.x *= inv[r]; a.y *= inv[r]; a.z *= inv[r]; a.w *= inv[r];
      ((float4*)sc[r])[k4] = a;
      arow[k4] = a;                      // coalesced 536 MB total write
    }
  }
  __syncthreads();

  // PV: heads[b,h,q0+r,e] = sum_k sc[r][k] * vs[b,k,e]; 4 k-chunks of 512.
  const int e = tid & 63, g = tid >> 6;
  const float* vsb = vs + (size_t)b * Sc * DKc + e;
  float acc[TQ];
#pragma unroll
  for (int r = 0; r < TQ; ++r) acc[r] = 0.f;
  const int kk4base = g * 128;           // float4 index into sc rows
#pragma unroll 2
  for (int kk4 = kk4base; kk4 < kk4base + 128; ++kk4) {
    const int kb = kk4 * 4;
    const float v0 = vsb[(size_t)(kb + 0) * DKc];
    const float v1 = vsb[(size_t)(kb + 1) * DKc];
    const float v2 = vsb[(size_t)(kb + 2) * DKc];
    const float v3 = vsb[(size_t)(kb + 3) * DKc];
#pragma unroll
    for (int r = 0; r < TQ; ++r) {
      const float4 s4 = ((const float4*)sc[r])[kk4];   // uniform -> broadcast
      acc[r] += s4.x * v0 + s4.y * v1 + s4.z * v2 + s4.w * v3;
    }
  }
#pragma unroll
  for (int r = 0; r < TQ; ++r) hred[g][r][e] = acc[r];
  __syncthreads();
  {  // TQ*DKc = 256 results, one per thread
    const int r = tid >> 6, ee = tid & 63;
    const float sum = hred[0][r][ee] + hred[1][r][ee] + hred[2][r][ee] + hred[3][r][ee];
    heads[((size_t)(b * Hc + h) * Sc + q0 + r) * DKc + ee] = sum;
  }
}

// One block per 8 (b,s) rows: mean over heads, project with Wh (8x Wh reuse).
__global__ __launch_bounds__(256) void out_kernel(
    const float* __restrict__ heads, const float* __restrict__ Wh,
    float* __restrict__ out) {
  const int bs0 = blockIdx.x * TR;
  const int b   = bs0 >> 11;
  const int s0  = bs0 & (Sc - 1);
  const int tid = threadIdx.x;
  __shared__ float havg[TR][DKc];        // 2 KB
  for (int t = tid; t < TR * DKc; t += 256) {
    const int r = t >> 6, ee = t & 63;
    float a = 0.f;
#pragma unroll
    for (int hh = 0; hh < Hc; ++hh)
      a += heads[((size_t)(b * Hc + hh) * Sc + s0 + r) * DKc + ee];
    havg[r][ee] = a * 0.25f;
  }
  __syncthreads();
  const float4* wh4 = (const float4*)(Wh + (size_t)tid * DKc);
  float acc[TR];
#pragma unroll
  for (int r = 0; r < TR; ++r) acc[r] = 0.f;
#pragma unroll
  for (int i = 0; i < DKc / 4; ++i) {
    const float4 w = wh4[i];
#pragma unroll
    for (int r = 0; r < TR; ++r) {
      const float4 a = ((const float4*)havg[r])[i];
      acc[r] += a.x * w.x + a.y * w.y + a.z * w.z + a.w * w.w;
    }
  }
#pragma unroll
  for (int r = 0; r < TR; ++r)
    out[(size_t)(bs0 + r) * DMc + tid] = acc[r];
}

extern "C" void kernel_launch(void* const* d_in, const int* in_sizes, int n_in,
                              void* d_out, int out_size, void* d_ws, size_t ws_size,
                              hipStream_t stream) {
  const float* q  = (const float*)d_in[0];
  const float* k  = (const float*)d_in[1];
  const float* v  = (const float*)d_in[2];
  const float* Wq = (const float*)d_in[3];
  const float* bq = (const float*)d_in[4];
  const float* Wk = (const float*)d_in[5];
  const float* bk = (const float*)d_in[6];
  const float* Wv = (const float*)d_in[7];
  const float* bv = (const float*)d_in[8];
  const float* Wh = (const float*)d_in[9];

  float* out  = (float*)d_out;                              // [B,S,256]
  float* attn = out + (size_t)Bc * Sc * DMc;                // [B,Sq,H,Sk]

  float* vs    = (float*)d_ws;                              // [B,S,64]      4 MB
  float* qs    = vs + (size_t)Bc * Sc * DKc;                // [B,H,S,64]   16 MB
  float* ksT   = qs + (size_t)Bc * Hc * Sc * DKc;           // [B,H,64,S]   16 MB
  float* heads = ksT + (size_t)Bc * Hc * Sc * DKc;          // [B,H,S,64]   16 MB

  proj_kernel<<<Bc * Sc / TR, 256, 0, stream>>>(q, k, v, Wq, bq, Wk, bk, Wv, bv,
                                                qs, ksT, vs);
  attn_kernel<<<dim3(Sc / TQ, Hc, Bc), 256, 0, stream>>>(qs, ksT, vs, attn, heads);
  out_kernel<<<Bc * Sc / TR, 256, 0, stream>>>(heads, Wh, out);
}

// Round 5
// 1152.988 us; speedup vs baseline: 3.2885x; 1.4018x over previous
//
#include <hip/hip_runtime.h>

typedef _Float16 half8 __attribute__((ext_vector_type(8)));
typedef _Float16 half2v __attribute__((ext_vector_type(2)));
typedef float f32x4 __attribute__((ext_vector_type(4)));

static constexpr int Bc  = 8;
static constexpr int Sc  = 2048;
static constexpr int Hc  = 4;
static constexpr int DKc = 64;
static constexpr int DMc = 256;
static constexpr int TR  = 8;    // (b,s) rows per proj/out block
static constexpr int QT  = 64;   // q-rows per attn block (16 per wave)
static constexpr int KT  = 128;  // k-tile
static constexpr int NKT = Sc / KT;  // 16

// One block per 8 consecutive (b,s) rows. Computes f16 projections:
// qs_h [B,H,S,64] (pre-scaled by 1/8), ks_h [B,H,S,64], vsT [B,64,S].
__global__ __launch_bounds__(256) void proj_kernel(
    const float* __restrict__ q, const float* __restrict__ k, const float* __restrict__ v,
    const float* __restrict__ Wq, const float* __restrict__ bq,
    const float* __restrict__ Wk, const float* __restrict__ bk,
    const float* __restrict__ Wv, const float* __restrict__ bv,
    _Float16* __restrict__ qs_h, _Float16* __restrict__ ks_h,
    _Float16* __restrict__ vsT) {
  const int bs0 = blockIdx.x * TR;
  const int b   = bs0 >> 11;
  const int s0  = bs0 & (Sc - 1);
  const int tid = threadIdx.x;
  __shared__ float qrow[TR][DMc], krow[TR][DMc], vrow[TR][DMc];  // 24 KB
  {
    const float4* qg = (const float4*)(q + (size_t)bs0 * DMc);
    const float4* kg = (const float4*)(k + (size_t)bs0 * DMc);
    const float4* vg = (const float4*)(v + (size_t)bs0 * DMc);
    float4* qls = (float4*)&qrow[0][0];
    float4* kls = (float4*)&krow[0][0];
    float4* vls = (float4*)&vrow[0][0];
#pragma unroll
    for (int i = 0; i < 2; ++i) {
      qls[tid + i * 256] = qg[tid + i * 256];
      kls[tid + i * 256] = kg[tid + i * 256];
      vls[tid + i * 256] = vg[tid + i * 256];
    }
  }
  __syncthreads();
  const int h = tid >> 6, e = tid & 63;
  const float4* wq4 = (const float4*)(Wq + (size_t)(h * DKc + e) * DMc);
  const float4* wk4 = (const float4*)(Wk + (size_t)(h * DKc + e) * DMc);
  const float4* wv4 = (const float4*)(Wv + (size_t)e * DMc);
  const int rv = h * 2;
  float accq[TR], acck[TR];
  float accv0 = 0.f, accv1 = 0.f;
#pragma unroll
  for (int r = 0; r < TR; ++r) { accq[r] = 0.f; acck[r] = 0.f; }
#pragma unroll 4
  for (int i = 0; i < DMc / 4; ++i) {
    const float4 wa = wq4[i], wc = wk4[i], wv = wv4[i];
#pragma unroll
    for (int r = 0; r < TR; ++r) {
      const float4 a = ((const float4*)qrow[r])[i];
      accq[r] += a.x * wa.x + a.y * wa.y + a.z * wa.z + a.w * wa.w;
      const float4 c = ((const float4*)krow[r])[i];
      acck[r] += c.x * wc.x + c.y * wc.y + c.z * wc.z + c.w * wc.w;
    }
    const float4 a0 = ((const float4*)vrow[rv])[i];
    const float4 a1 = ((const float4*)vrow[rv + 1])[i];
    accv0 += a0.x * wv.x + a0.y * wv.y + a0.z * wv.z + a0.w * wv.w;
    accv1 += a1.x * wv.x + a1.y * wv.y + a1.z * wv.z + a1.w * wv.w;
  }
  const float bqv = bq[h * DKc + e], bkv = bk[h * DKc + e];
#pragma unroll
  for (int r = 0; r < TR; ++r) {
    const size_t row = (size_t)(b * Hc + h) * Sc + s0 + r;
    qs_h[row * DKc + e] = (_Float16)((accq[r] + bqv) * 0.125f);
    ks_h[row * DKc + e] = (_Float16)(acck[r] + bkv);
  }
  const float bvv = bv[e];
  half2v hv;
  hv[0] = (_Float16)(accv0 + bvv);
  hv[1] = (_Float16)(accv1 + bvv);
  *(half2v*)&vsT[(size_t)(b * DKc + e) * Sc + s0 + rv] = hv;
}

// One block per (b,h,64 q-rows); 4 independent waves x 16 q-rows.
// Pass1: QK^T MFMA -> running row max/sumexp. Pass2: recompute QK^T,
// write fp32 attn, stage p f16 in LDS, PV via MFMA, fp32 O accum.
__global__ __launch_bounds__(256) void attn_kernel(
    const _Float16* __restrict__ qs_h, const _Float16* __restrict__ ks_h,
    const _Float16* __restrict__ vsT, float* __restrict__ attn,
    float* __restrict__ heads) {
  const int q0  = blockIdx.x * QT;
  const int h   = blockIdx.y;
  const int b   = blockIdx.z;
  const int tid = threadIdx.x;
  const int wid = tid >> 6, lane = tid & 63;
  const int lq  = lane & 15, lg = lane >> 4;
  const int qb  = q0 + wid * 16;

  __shared__ _Float16 Pl[4][16][136];   // per-wave p tile, padded (17 KB)

  const size_t bh = (size_t)(b * Hc + h) * Sc;
  // Q A-fragments (row = lq), 2 e-chunks of 32; reused for every k-tile.
  const half8 aq0 = *(const half8*)&qs_h[(bh + qb + lq) * DKc + lg * 8];
  const half8 aq1 = *(const half8*)&qs_h[(bh + qb + lq) * DKc + 32 + lg * 8];

  float m[4], l[4];
#pragma unroll
  for (int j = 0; j < 4; ++j) { m[j] = -1e30f; l[j] = 0.f; }

  // ---------------- pass 1: softmax scalars ----------------
  for (int kt = 0; kt < NKT; ++kt) {
    const int k0 = kt * KT;
    f32x4 lgt[8];
#pragma unroll
    for (int nt = 0; nt < 8; ++nt) {
      f32x4 c = {0.f, 0.f, 0.f, 0.f};
      const _Float16* kp = &ks_h[(bh + k0 + nt * 16 + lq) * DKc + lg * 8];
      c = __builtin_amdgcn_mfma_f32_16x16x32_f16(aq0, *(const half8*)kp, c, 0, 0, 0);
      c = __builtin_amdgcn_mfma_f32_16x16x32_f16(aq1, *(const half8*)(kp + 32), c, 0, 0, 0);
      lgt[nt] = c;
    }
#pragma unroll
    for (int j = 0; j < 4; ++j) {
      float tm = lgt[0][j];
#pragma unroll
      for (int nt = 1; nt < 8; ++nt) tm = fmaxf(tm, lgt[nt][j]);
#pragma unroll
      for (int mk = 1; mk < 16; mk <<= 1) tm = fmaxf(tm, __shfl_xor(tm, mk, 64));
      const float nm = fmaxf(m[j], tm);
      float ts = 0.f;
#pragma unroll
      for (int nt = 0; nt < 8; ++nt) ts += __expf(lgt[nt][j] - nm);
#pragma unroll
      for (int mk = 1; mk < 16; mk <<= 1) ts += __shfl_xor(ts, mk, 64);
      l[j] = l[j] * __expf(m[j] - nm) + ts;
      m[j] = nm;
    }
  }
  float inv[4];
#pragma unroll
  for (int j = 0; j < 4; ++j) inv[j] = 1.f / l[j];

  // ---------------- pass 2: attn write + PV ----------------
  f32x4 oacc[4];
#pragma unroll
  for (int et = 0; et < 4; ++et) oacc[et] = (f32x4){0.f, 0.f, 0.f, 0.f};

  for (int kt = 0; kt < NKT; ++kt) {
    const int k0 = kt * KT;
#pragma unroll
    for (int nt = 0; nt < 8; ++nt) {
      f32x4 c = {0.f, 0.f, 0.f, 0.f};
      const _Float16* kp = &ks_h[(bh + k0 + nt * 16 + lq) * DKc + lg * 8];
      c = __builtin_amdgcn_mfma_f32_16x16x32_f16(aq0, *(const half8*)kp, c, 0, 0, 0);
      c = __builtin_amdgcn_mfma_f32_16x16x32_f16(aq1, *(const half8*)(kp + 32), c, 0, 0, 0);
#pragma unroll
      for (int j = 0; j < 4; ++j) {
        const float p = __expf(c[j] - m[j]) * inv[j];
        attn[((size_t)(b * Sc + qb + lg * 4 + j) * Hc + h) * Sc + k0 + nt * 16 + lq] = p;
        Pl[wid][lg * 4 + j][nt * 16 + lq] = (_Float16)p;
      }
    }
    // wave-internal LDS write->read ordering (per-wave tile, no barrier needed)
    asm volatile("s_waitcnt lgkmcnt(0)" ::: "memory");
#pragma unroll
    for (int ch = 0; ch < 4; ++ch) {
      const half8 ap = *(const half8*)&Pl[wid][lq][ch * 32 + lg * 8];
#pragma unroll
      for (int et = 0; et < 4; ++et) {
        const half8 bv = *(const half8*)&vsT[((size_t)b * DKc + et * 16 + lq) * Sc + k0 + ch * 32 + lg * 8];
        oacc[et] = __builtin_amdgcn_mfma_f32_16x16x32_f16(ap, bv, oacc[et], 0, 0, 0);
      }
    }
    asm volatile("" ::: "memory");
  }
#pragma unroll
  for (int et = 0; et < 4; ++et)
#pragma unroll
    for (int j = 0; j < 4; ++j)
      heads[(bh + qb + lg * 4 + j) * DKc + et * 16 + lq] = oacc[et][j];
}

// One block per 8 (b,s) rows: mean over heads, project with Wh.
__global__ __launch_bounds__(256) void out_kernel(
    const float* __restrict__ heads, const float* __restrict__ Wh,
    float* __restrict__ out) {
  const int bs0 = blockIdx.x * TR;
  const int b   = bs0 >> 11;
  const int s0  = bs0 & (Sc - 1);
  const int tid = threadIdx.x;
  __shared__ float havg[TR][DKc];
  for (int t = tid; t < TR * DKc; t += 256) {
    const int r = t >> 6, ee = t & 63;
    float a = 0.f;
#pragma unroll
    for (int hh = 0; hh < Hc; ++hh)
      a += heads[((size_t)(b * Hc + hh) * Sc + s0 + r) * DKc + ee];
    havg[r][ee] = a * 0.25f;
  }
  __syncthreads();
  const float4* wh4 = (const float4*)(Wh + (size_t)tid * DKc);
  float acc[TR];
#pragma unroll
  for (int r = 0; r < TR; ++r) acc[r] = 0.f;
#pragma unroll
  for (int i = 0; i < DKc / 4; ++i) {
    const float4 w = wh4[i];
#pragma unroll
    for (int r = 0; r < TR; ++r) {
      const float4 a = ((const float4*)havg[r])[i];
      acc[r] += a.x * w.x + a.y * w.y + a.z * w.z + a.w * w.w;
    }
  }
#pragma unroll
  for (int r = 0; r < TR; ++r)
    out[(size_t)(bs0 + r) * DMc + tid] = acc[r];
}

extern "C" void kernel_launch(void* const* d_in, const int* in_sizes, int n_in,
                              void* d_out, int out_size, void* d_ws, size_t ws_size,
                              hipStream_t stream) {
  const float* q  = (const float*)d_in[0];
  const float* k  = (const float*)d_in[1];
  const float* v  = (const float*)d_in[2];
  const float* Wq = (const float*)d_in[3];
  const float* bq = (const float*)d_in[4];
  const float* Wk = (const float*)d_in[5];
  const float* bk = (const float*)d_in[6];
  const float* Wv = (const float*)d_in[7];
  const float* bv = (const float*)d_in[8];
  const float* Wh = (const float*)d_in[9];

  float* out  = (float*)d_out;                              // [B,S,256]
  float* attn = out + (size_t)Bc * Sc * DMc;                // [B,Sq,H,Sk]

  const size_t NQ = (size_t)Bc * Hc * Sc * DKc;             // 4M elems
  _Float16* qs_h = (_Float16*)d_ws;                         // 8 MB
  _Float16* ks_h = qs_h + NQ;                               // 8 MB
  _Float16* vsT  = ks_h + NQ;                               // [B,64,S] 2 MB
  float* heads   = (float*)(vsT + (size_t)Bc * DKc * Sc);   // 16 MB

  proj_kernel<<<Bc * Sc / TR, 256, 0, stream>>>(q, k, v, Wq, bq, Wk, bk, Wv, bv,
                                                qs_h, ks_h, vsT);
  attn_kernel<<<dim3(Sc / QT, Hc, Bc), 256, 0, stream>>>(qs_h, ks_h, vsT, attn, heads);
  out_kernel<<<Bc * Sc / TR, 256, 0, stream>>>(heads, Wh, out);
}

// Round 6
// 1080.400 us; speedup vs baseline: 3.5095x; 1.0672x over previous
//
#include <hip/hip_runtime.h>

typedef _Float16 half8 __attribute__((ext_vector_type(8)));
typedef _Float16 half2v __attribute__((ext_vector_type(2)));
typedef float f32x4 __attribute__((ext_vector_type(4)));

static constexpr int Bc  = 8;
static constexpr int Sc  = 2048;
static constexpr int Hc  = 4;
static constexpr int DKc = 64;
static constexpr int DMc = 256;
static constexpr int TR  = 8;    // (b,s) rows per proj/out block
static constexpr int QT  = 64;   // q-rows per attn block (16 per wave)
static constexpr int KT  = 128;  // k-tile
static constexpr int NKT = Sc / KT;  // 16

// One block per 8 consecutive (b,s) rows. Computes f16 projections:
// qs_h [B,H,S,64] (pre-scaled by 1/8), ks_h [B,H,S,64], vsT [B,64,S].
__global__ __launch_bounds__(256) void proj_kernel(
    const float* __restrict__ q, const float* __restrict__ k, const float* __restrict__ v,
    const float* __restrict__ Wq, const float* __restrict__ bq,
    const float* __restrict__ Wk, const float* __restrict__ bk,
    const float* __restrict__ Wv, const float* __restrict__ bv,
    _Float16* __restrict__ qs_h, _Float16* __restrict__ ks_h,
    _Float16* __restrict__ vsT) {
  const int bs0 = blockIdx.x * TR;
  const int b   = bs0 >> 11;
  const int s0  = bs0 & (Sc - 1);
  const int tid = threadIdx.x;
  __shared__ float qrow[TR][DMc], krow[TR][DMc], vrow[TR][DMc];  // 24 KB
  {
    const float4* qg = (const float4*)(q + (size_t)bs0 * DMc);
    const float4* kg = (const float4*)(k + (size_t)bs0 * DMc);
    const float4* vg = (const float4*)(v + (size_t)bs0 * DMc);
    float4* qls = (float4*)&qrow[0][0];
    float4* kls = (float4*)&krow[0][0];
    float4* vls = (float4*)&vrow[0][0];
#pragma unroll
    for (int i = 0; i < 2; ++i) {
      qls[tid + i * 256] = qg[tid + i * 256];
      kls[tid + i * 256] = kg[tid + i * 256];
      vls[tid + i * 256] = vg[tid + i * 256];
    }
  }
  __syncthreads();
  const int h = tid >> 6, e = tid & 63;
  const float4* wq4 = (const float4*)(Wq + (size_t)(h * DKc + e) * DMc);
  const float4* wk4 = (const float4*)(Wk + (size_t)(h * DKc + e) * DMc);
  const float4* wv4 = (const float4*)(Wv + (size_t)e * DMc);
  const int rv = h * 2;
  float accq[TR], acck[TR];
  float accv0 = 0.f, accv1 = 0.f;
#pragma unroll
  for (int r = 0; r < TR; ++r) { accq[r] = 0.f; acck[r] = 0.f; }
#pragma unroll 4
  for (int i = 0; i < DMc / 4; ++i) {
    const float4 wa = wq4[i], wc = wk4[i], wv = wv4[i];
#pragma unroll
    for (int r = 0; r < TR; ++r) {
      const float4 a = ((const float4*)qrow[r])[i];
      accq[r] += a.x * wa.x + a.y * wa.y + a.z * wa.z + a.w * wa.w;
      const float4 c = ((const float4*)krow[r])[i];
      acck[r] += c.x * wc.x + c.y * wc.y + c.z * wc.z + c.w * wc.w;
    }
    const float4 a0 = ((const float4*)vrow[rv])[i];
    const float4 a1 = ((const float4*)vrow[rv + 1])[i];
    accv0 += a0.x * wv.x + a0.y * wv.y + a0.z * wv.z + a0.w * wv.w;
    accv1 += a1.x * wv.x + a1.y * wv.y + a1.z * wv.z + a1.w * wv.w;
  }
  const float bqv = bq[h * DKc + e], bkv = bk[h * DKc + e];
#pragma unroll
  for (int r = 0; r < TR; ++r) {
    const size_t row = (size_t)(b * Hc + h) * Sc + s0 + r;
    qs_h[row * DKc + e] = (_Float16)((accq[r] + bqv) * 0.125f);
    ks_h[row * DKc + e] = (_Float16)(acck[r] + bkv);
  }
  const float bvv = bv[e];
  half2v hv;
  hv[0] = (_Float16)(accv0 + bvv);
  hv[1] = (_Float16)(accv1 + bvv);
  *(half2v*)&vsT[(size_t)(b * DKc + e) * Sc + s0 + rv] = hv;
}

// One block per (b,h,64 q-rows); 4 independent waves x 16 q-rows.
// Pass1: QK^T MFMA -> PER-LANE online (m,l), one cross-lane merge at end.
// Pass2: recompute QK^T, p = exp(s - (m+log l)), write fp32 attn, stage p
// f16 in per-wave LDS tile, PV via MFMA with prefetched V fragments.
__global__ __launch_bounds__(256, 4) void attn_kernel(
    const _Float16* __restrict__ qs_h, const _Float16* __restrict__ ks_h,
    const _Float16* __restrict__ vsT, float* __restrict__ attn,
    float* __restrict__ heads) {
  const int q0  = blockIdx.x * QT;
  const int h   = blockIdx.y;
  const int b   = blockIdx.z;
  const int tid = threadIdx.x;
  const int wid = tid >> 6, lane = tid & 63;
  const int lq  = lane & 15, lg = lane >> 4;
  const int qb  = q0 + wid * 16;

  __shared__ _Float16 Pl[4][16][136];   // per-wave p tile, padded (17 KB)

  const size_t bh = (size_t)(b * Hc + h) * Sc;
  const half8 aq0 = *(const half8*)&qs_h[(bh + qb + lq) * DKc + lg * 8];
  const half8 aq1 = *(const half8*)&qs_h[(bh + qb + lq) * DKc + 32 + lg * 8];

  float m[4], l[4];
#pragma unroll
  for (int j = 0; j < 4; ++j) { m[j] = -1e30f; l[j] = 0.f; }

  // ---------------- pass 1: per-lane online softmax scalars ----------------
#pragma unroll 2
  for (int kt = 0; kt < NKT; ++kt) {
    const int k0 = kt * KT;
    f32x4 lgt[8];
#pragma unroll
    for (int nt = 0; nt < 8; ++nt) {
      f32x4 c = {0.f, 0.f, 0.f, 0.f};
      const _Float16* kp = &ks_h[(bh + k0 + nt * 16 + lq) * DKc + lg * 8];
      c = __builtin_amdgcn_mfma_f32_16x16x32_f16(aq0, *(const half8*)kp, c, 0, 0, 0);
      c = __builtin_amdgcn_mfma_f32_16x16x32_f16(aq1, *(const half8*)(kp + 32), c, 0, 0, 0);
      lgt[nt] = c;
    }
#pragma unroll
    for (int j = 0; j < 4; ++j) {
      float tm = lgt[0][j];
#pragma unroll
      for (int nt = 1; nt < 8; ++nt) tm = fmaxf(tm, lgt[nt][j]);
      const float nm = fmaxf(m[j], tm);
      float ts = 0.f;
#pragma unroll
      for (int nt = 0; nt < 8; ++nt) ts += __expf(lgt[nt][j] - nm);
      l[j] = l[j] * __expf(m[j] - nm) + ts;   // no cross-lane ops in the loop
      m[j] = nm;
    }
  }
  // single cross-lane merge over the 16-lane lq group (bits 0..3)
  float mm[4];
#pragma unroll
  for (int j = 0; j < 4; ++j) {
#pragma unroll
    for (int mk = 1; mk < 16; mk <<= 1) {
      const float om = __shfl_xor(m[j], mk, 64);
      const float ol = __shfl_xor(l[j], mk, 64);
      const float nm = fmaxf(m[j], om);
      l[j] = l[j] * __expf(m[j] - nm) + ol * __expf(om - nm);
      m[j] = nm;
    }
    mm[j] = m[j] + __logf(l[j]);   // p = exp(s - mm) is already normalized
  }

  // ---------------- pass 2: attn write + PV ----------------
  f32x4 oacc[4];
#pragma unroll
  for (int et = 0; et < 4; ++et) oacc[et] = (f32x4){0.f, 0.f, 0.f, 0.f};

  const _Float16* vb = vsT + (size_t)b * DKc * Sc;
  for (int kt = 0; kt < NKT; ++kt) {
    const int k0 = kt * KT;
    // prefetch V fragments for ch 0-1 early (latency hides under QK+exp)
    half8 bva[2][4];
#pragma unroll
    for (int ch = 0; ch < 2; ++ch)
#pragma unroll
      for (int et = 0; et < 4; ++et)
        bva[ch][et] = *(const half8*)&vb[(size_t)(et * 16 + lq) * Sc + k0 + ch * 32 + lg * 8];

#pragma unroll
    for (int nt = 0; nt < 8; ++nt) {
      f32x4 c = {0.f, 0.f, 0.f, 0.f};
      const _Float16* kp = &ks_h[(bh + k0 + nt * 16 + lq) * DKc + lg * 8];
      c = __builtin_amdgcn_mfma_f32_16x16x32_f16(aq0, *(const half8*)kp, c, 0, 0, 0);
      c = __builtin_amdgcn_mfma_f32_16x16x32_f16(aq1, *(const half8*)(kp + 32), c, 0, 0, 0);
#pragma unroll
      for (int j = 0; j < 4; ++j) {
        const float p = __expf(c[j] - mm[j]);
        attn[((size_t)(b * Sc + qb + lg * 4 + j) * Hc + h) * Sc + k0 + nt * 16 + lq] = p;
        Pl[wid][lg * 4 + j][nt * 16 + lq] = (_Float16)p;
      }
    }
    // wave-internal LDS write->read ordering (per-wave tile; V prefetch above
    // is pinned BEFORE this clobber, ds_reads below cannot hoist above it)
    asm volatile("s_waitcnt lgkmcnt(0)" ::: "memory");
    __builtin_amdgcn_s_setprio(1);
#pragma unroll
    for (int ch = 0; ch < 2; ++ch) {
      const half8 ap = *(const half8*)&Pl[wid][lq][ch * 32 + lg * 8];
#pragma unroll
      for (int et = 0; et < 4; ++et)
        oacc[et] = __builtin_amdgcn_mfma_f32_16x16x32_f16(ap, bva[ch][et], oacc[et], 0, 0, 0);
    }
#pragma unroll
    for (int ch = 2; ch < 4; ++ch) {
      const half8 ap = *(const half8*)&Pl[wid][lq][ch * 32 + lg * 8];
#pragma unroll
      for (int et = 0; et < 4; ++et) {
        const half8 bv = *(const half8*)&vb[(size_t)(et * 16 + lq) * Sc + k0 + ch * 32 + lg * 8];
        oacc[et] = __builtin_amdgcn_mfma_f32_16x16x32_f16(ap, bv, oacc[et], 0, 0, 0);
      }
    }
    __builtin_amdgcn_s_setprio(0);
  }
#pragma unroll
  for (int et = 0; et < 4; ++et)
#pragma unroll
    for (int j = 0; j < 4; ++j)
      heads[(bh + qb + lg * 4 + j) * DKc + et * 16 + lq] = oacc[et][j];
}

// One block per 8 (b,s) rows: mean over heads, project with Wh.
__global__ __launch_bounds__(256) void out_kernel(
    const float* __restrict__ heads, const float* __restrict__ Wh,
    float* __restrict__ out) {
  const int bs0 = blockIdx.x * TR;
  const int b   = bs0 >> 11;
  const int s0  = bs0 & (Sc - 1);
  const int tid = threadIdx.x;
  __shared__ float havg[TR][DKc];
  for (int t = tid; t < TR * DKc; t += 256) {
    const int r = t >> 6, ee = t & 63;
    float a = 0.f;
#pragma unroll
    for (int hh = 0; hh < Hc; ++hh)
      a += heads[((size_t)(b * Hc + hh) * Sc + s0 + r) * DKc + ee];
    havg[r][ee] = a * 0.25f;
  }
  __syncthreads();
  const float4* wh4 = (const float4*)(Wh + (size_t)tid * DKc);
  float acc[TR];
#pragma unroll
  for (int r = 0; r < TR; ++r) acc[r] = 0.f;
#pragma unroll
  for (int i = 0; i < DKc / 4; ++i) {
    const float4 w = wh4[i];
#pragma unroll
    for (int r = 0; r < TR; ++r) {
      const float4 a = ((const float4*)havg[r])[i];
      acc[r] += a.x * w.x + a.y * w.y + a.z * w.z + a.w * w.w;
    }
  }
#pragma unroll
  for (int r = 0; r < TR; ++r)
    out[(size_t)(bs0 + r) * DMc + tid] = acc[r];
}

extern "C" void kernel_launch(void* const* d_in, const int* in_sizes, int n_in,
                              void* d_out, int out_size, void* d_ws, size_t ws_size,
                              hipStream_t stream) {
  const float* q  = (const float*)d_in[0];
  const float* k  = (const float*)d_in[1];
  const float* v  = (const float*)d_in[2];
  const float* Wq = (const float*)d_in[3];
  const float* bq = (const float*)d_in[4];
  const float* Wk = (const float*)d_in[5];
  const float* bk = (const float*)d_in[6];
  const float* Wv = (const float*)d_in[7];
  const float* bv = (const float*)d_in[8];
  const float* Wh = (const float*)d_in[9];

  float* out  = (float*)d_out;                              // [B,S,256]
  float* attn = out + (size_t)Bc * Sc * DMc;                // [B,Sq,H,Sk]

  const size_t NQ = (size_t)Bc * Hc * Sc * DKc;             // 4M elems
  _Float16* qs_h = (_Float16*)d_ws;                         // 8 MB
  _Float16* ks_h = qs_h + NQ;                               // 8 MB
  _Float16* vsT  = ks_h + NQ;                               // [B,64,S] 2 MB
  float* heads   = (float*)(vsT + (size_t)Bc * DKc * Sc);   // 16 MB

  proj_kernel<<<Bc * Sc / TR, 256, 0, stream>>>(q, k, v, Wq, bq, Wk, bk, Wv, bv,
                                                qs_h, ks_h, vsT);
  attn_kernel<<<dim3(Sc / QT, Hc, Bc), 256, 0, stream>>>(qs_h, ks_h, vsT, attn, heads);
  out_kernel<<<Bc * Sc / TR, 256, 0, stream>>>(heads, Wh, out);
}